// Round 1
// baseline (232.210 us; speedup 1.0000x reference)
//
#include <hip/hip_runtime.h>

typedef short v8s __attribute__((ext_vector_type(8)));
typedef float v4f __attribute__((ext_vector_type(4)));
typedef unsigned short u16;

#define NPIX 1024
#define EPS 1e-5f

__device__ __forceinline__ float bf2f(u16 u){
  return __uint_as_float(((unsigned)u) << 16);
}
__device__ __forceinline__ u16 f2bf(float f){
  unsigned b = __float_as_uint(f);
  b += 0x7FFF + ((b >> 16) & 1);   // RNE
  return (u16)(b >> 16);
}
// pack two f32 -> two bf16 in one VALU op (RNE, same bits as f2bf)
__device__ __forceinline__ unsigned cvtpk(float lo, float hi){
  unsigned r;
  asm("v_cvt_pk_bf16_f32 %0, %1, %2" : "=v"(r) : "v"(lo), "v"(hi));
  return r;
}

// ---------------------------------------------------------------------------
// Plain-bf16 GEMM+BN: dst = BN(src @ W^T); src f32 (B,Cin,1024), W f32.
// Staging converts f32->bf16 via v_cvt_pk_bf16_f32 (1 op / 2 elems).
// grid: (16, Cout/64, B), block 256 (4 waves).
// ---------------------------------------------------------------------------
template<bool OUT_F32>
__global__ __launch_bounds__(256) void gemm_bn(
    const float* __restrict__ src, const float* __restrict__ W,
    const float* __restrict__ gam, const float* __restrict__ bet,
    const float* __restrict__ mu,  const float* __restrict__ var,
    u16* __restrict__ bout, float* __restrict__ fout, int Cin, int Cout)
{
  const int n0 = blockIdx.x * 64;
  const int o0 = blockIdx.y * 64;
  const int b  = blockIdx.z;
  const int tid = threadIdx.x;
  const int w = tid >> 6, lane = tid & 63, col = lane & 15, quad = lane >> 4;

  __shared__ u16 Alds[64 * 40];   // [m][k], stride 40 (80B rows, 16B aligned)
  __shared__ u16 Blds[32 * 68];   // [k][n], stride 68 (2-way u16 reads = free)

  v4f acc[4];
#pragma unroll
  for (int i = 0; i < 4; i++) acc[i] = (v4f){0.f, 0.f, 0.f, 0.f};

  const int arow = tid >> 2, acs = (tid & 3) * 8;   // A staging: 64x32
  const int brow = tid >> 3, bns = (tid & 7) * 8;   // B staging: 32x64

  for (int k0 = 0; k0 < Cin; k0 += 32) {
    __syncthreads();
    {   // A tile: W rows f32 -> bf16 (packed converts)
      const float* p = W + (size_t)(o0 + arow) * Cin + k0 + acs;
      float4 t0 = ((const float4*)p)[0];
      float4 t1 = ((const float4*)p)[1];
      uint4 pk;
      pk.x = cvtpk(t0.x, t0.y);
      pk.y = cvtpk(t0.z, t0.w);
      pk.z = cvtpk(t1.x, t1.y);
      pk.w = cvtpk(t1.z, t1.w);
      *(uint4*)(&Alds[arow * 40 + acs]) = pk;   // 16B aligned (80B rows)
    }
    {   // B tile: src rows f32 -> bf16 (packed converts)
      const float* p = src + ((size_t)b * Cin + k0 + brow) * NPIX + n0 + bns;
      float4 t0 = ((const float4*)p)[0];
      float4 t1 = ((const float4*)p)[1];
      uint2 lo, hi;
      lo.x = cvtpk(t0.x, t0.y);
      lo.y = cvtpk(t0.z, t0.w);
      hi.x = cvtpk(t1.x, t1.y);
      hi.y = cvtpk(t1.z, t1.w);
      *(uint2*)(&Blds[brow * 68 + bns])     = lo;  // 8B aligned (136B rows)
      *(uint2*)(&Blds[brow * 68 + bns + 4]) = hi;
    }
    __syncthreads();

    v8s bf;
#pragma unroll
    for (int jj = 0; jj < 8; jj++)
      bf[jj] = (short)Blds[(quad * 8 + jj) * 68 + w * 16 + col];
#pragma unroll
    for (int mt = 0; mt < 4; mt++) {
      v8s af = *(const v8s*)(&Alds[(mt * 16 + col) * 40 + quad * 8]);
      acc[mt] = __builtin_amdgcn_mfma_f32_16x16x32_bf16(af, bf, acc[mt], 0, 0, 0);
    }
  }

  const int n = n0 + w * 16 + col;
#pragma unroll
  for (int mt = 0; mt < 4; mt++) {
#pragma unroll
    for (int r = 0; r < 4; r++) {
      int o = o0 + mt * 16 + quad * 4 + r;
      float inv = rsqrtf(var[o] + EPS) * gam[o];
      float val = acc[mt][r] * inv + (bet[o] - mu[o] * inv);
      size_t idx = (size_t)(b * Cout + o) * NPIX + n;
      if (OUT_F32) fout[idx] = val;
      else         bout[idx] = f2bf(val);
    }
  }
}

// ---------------------------------------------------------------------------
// MFMA flash attention, no-max softmax (scores bounded), all-bf16 qkv.
// Swapped QK^T (mfma(K,Q)) => each lane holds 4 consecutive keys of ONE
// query: P-store is 2 cvt_pk + one 8B ds_write (was 16 f2bf ops + 4 b16
// scatters). exp2-direct: Q pre-scaled by SCALE*log2(e). V read straight
// from global (L2-resident, 64B-contiguous per quad) -- no Vl staging.
// grid: (16 q-tiles, 8 heads, 16 batch), block 256 (4 waves, 16 q/wave).
// ---------------------------------------------------------------------------
__global__ __launch_bounds__(256) void attn_mfma_kernel(
    const u16* __restrict__ qkv, float* __restrict__ att)
{
  const int qt = blockIdx.x, h = blockIdx.y, b = blockIdx.z;
  const int tid = threadIdx.x, w = tid >> 6, lane = tid & 63;
  const int col = lane & 15, quad = lane >> 4;
  const u16* base = qkv + (size_t)(b * 512 + h * 64) * NPIX;

  __shared__ u16 Kt[64 * 24];      // [j][k] transposed, stride 24
  __shared__ u16 Pl[4][16 * 72];   // per-wave P round-trip, [query][j]

  const int q0 = qt * 64 + w * 16;

  // Q B-fragment (loop-invariant): B[n=q=col][k=quad*8+jj], k>=16 zero.
  // Scale = SCALE * log2(e) so scores feed exp2 directly.
  v8s qf = (v8s){0, 0, 0, 0, 0, 0, 0, 0};
  if (quad < 2) {
#pragma unroll
    for (int jj = 0; jj < 8; jj++) {
      int k = quad * 8 + jj;
      qf[jj] = (short)f2bf(bf2f(base[(size_t)k * NPIX + q0 + col])
                           * 0.36067376022224085f);
    }
  }

  float lsum = 0.f;
  v4f o_acc[2];
  o_acc[0] = (v4f){0, 0, 0, 0};
  o_acc[1] = (v4f){0, 0, 0, 0};

  const int kk4 = w * 4;                         // wave w stages k rows w*4..+3

  for (int j0 = 0; j0 < 1024; j0 += 64) {
    __syncthreads();
    {   // stage K transposed: Kt[j][k]
      ushort4 t;
      t.x = base[(size_t)(16 + kk4 + 0) * NPIX + j0 + lane];
      t.y = base[(size_t)(16 + kk4 + 1) * NPIX + j0 + lane];
      t.z = base[(size_t)(16 + kk4 + 2) * NPIX + j0 + lane];
      t.w = base[(size_t)(16 + kk4 + 3) * NPIX + j0 + lane];
      *(ushort4*)(&Kt[lane * 24 + kk4]) = t;
    }
    __syncthreads();

    // scores + exp2 + packed P-store.
    // s = mfma(K, Q): D[m=key][n=query] -> row=quad*4+r is key, col is query.
#pragma unroll
    for (int jt = 0; jt < 4; jt++) {
      v8s kf = (v8s){0, 0, 0, 0, 0, 0, 0, 0};
      if (quad < 2)
        kf = *(const v8s*)(&Kt[(jt * 16 + col) * 24 + quad * 8]);
      v4f z = (v4f){0, 0, 0, 0};
      v4f s = __builtin_amdgcn_mfma_f32_16x16x32_bf16(kf, qf, z, 0, 0, 0);
      float p0 = exp2f(s[0]);           // native v_exp_f32, scale pre-folded
      float p1 = exp2f(s[1]);
      float p2 = exp2f(s[2]);
      float p3 = exp2f(s[3]);
      lsum += (p0 + p1) + (p2 + p3);
      uint2 pk;
      pk.x = cvtpk(p0, p1);
      pk.y = cvtpk(p2, p3);
      // Pl[q=col][j = jt*16 + quad*4 .. +3]: 8B store, 2-way banks (free)
      *(uint2*)(&Pl[w][col * 72 + jt * 16 + quad * 4]) = pk;
    }

    // PV: D[m=query][n=d]; pf from LDS (b128), vf straight from global.
#pragma unroll
    for (int T = 0; T < 2; T++) {
      v8s pf = *(const v8s*)(&Pl[w][col * 72 + T * 32 + quad * 8]);
#pragma unroll
      for (int dt = 0; dt < 2; dt++) {
        v8s vf = *(const v8s*)(base + (size_t)(32 + dt * 16 + col) * NPIX +
                               j0 + T * 32 + quad * 8);
        o_acc[dt] = __builtin_amdgcn_mfma_f32_16x16x32_bf16(pf, vf, o_acc[dt], 0, 0, 0);
      }
    }
  }

  // epilogue: cross-quad row-sum (each lane owns query q=col), then fetch
  // the sums for q=quad*4+r to match the o_acc D-layout, normalize, store.
  lsum += __shfl_xor(lsum, 16);
  lsum += __shfl_xor(lsum, 32);
  float ls[4];
#pragma unroll
  for (int r = 0; r < 4; r++) ls[r] = __shfl(lsum, quad * 4 + r);
#pragma unroll
  for (int dt = 0; dt < 2; dt++) {
    float4 pack;
    pack.x = o_acc[dt][0] * (1.f / ls[0]);
    pack.y = o_acc[dt][1] * (1.f / ls[1]);
    pack.z = o_acc[dt][2] * (1.f / ls[2]);
    pack.w = o_acc[dt][3] * (1.f / ls[3]);
    *(float4*)(&att[(size_t)(b * 256 + h * 32 + dt * 16 + col) * NPIX +
                    q0 + quad * 4]) = pack;
  }
}

// ---------------------------------------------------------------------------
// Depthwise 3x3 centered unflipped + BN; att(f32) += BN(conv(v)).
// grid: (4, 256, 16), block 256.
// ---------------------------------------------------------------------------
__global__ __launch_bounds__(256) void conv_bn_add_center(
    const u16* __restrict__ qkv, float* __restrict__ att,
    const float* __restrict__ wpos,
    const float* __restrict__ gam, const float* __restrict__ bet,
    const float* __restrict__ mu,  const float* __restrict__ var)
{
  const int c = blockIdx.y, b = blockIdx.z;
  const int p = blockIdx.x * 256 + threadIdx.x;
  const int y = p >> 5, x = p & 31;
  const u16* v = qkv + (size_t)(b * 512 + (c >> 5) * 64 + 32 + (c & 31)) * NPIX;

  float accv = 0.f;
#pragma unroll
  for (int ky = 0; ky < 3; ky++) {
    int yy = y + ky - 1;
    if (yy < 0 || yy > 31) continue;
#pragma unroll
    for (int kx = 0; kx < 3; kx++) {
      int xx = x + kx - 1;
      if (xx < 0 || xx > 31) continue;
      accv += bf2f(v[yy * 32 + xx]) * wpos[c * 9 + ky * 3 + kx];
    }
  }
  float inv = rsqrtf(var[c] + EPS) * gam[c];
  float add = bet[c] - mu[c] * inv;
  size_t idx = (size_t)(b * 256 + c) * NPIX + p;
  att[idx] = accv * inv + add + att[idx];
}

// ---------------------------------------------------------------------------
extern "C" void kernel_launch(void* const* d_in, const int* in_sizes, int n_in,
                              void* d_out, int out_size, void* d_ws, size_t ws_size,
                              hipStream_t stream)
{
  (void)in_sizes; (void)n_in; (void)out_size; (void)ws_size;
  const float* x      = (const float*)d_in[0];
  const float* w_qkv  = (const float*)d_in[1];
  const float* g_qkv  = (const float*)d_in[2];
  const float* b_qkv  = (const float*)d_in[3];
  const float* m_qkv  = (const float*)d_in[4];
  const float* v_qkv  = (const float*)d_in[5];
  const float* w_pos  = (const float*)d_in[6];
  const float* g_pos  = (const float*)d_in[7];
  const float* b_pos  = (const float*)d_in[8];
  const float* m_pos  = (const float*)d_in[9];
  const float* v_pos  = (const float*)d_in[10];
  const float* w_proj = (const float*)d_in[11];
  const float* g_proj = (const float*)d_in[12];
  const float* b_proj = (const float*)d_in[13];
  const float* m_proj = (const float*)d_in[14];
  const float* v_proj = (const float*)d_in[15];

  // Buffer plan:
  //   qkv bf16 (16,512,1024): ws[0..16MB)
  //   att f32  (16,256,1024): x buffer (dead after gemm1; harness restores)
  u16*   qkv = (u16*)d_ws;
  float* att = (float*)d_in[0];

  // 1. qkv = BN(x @ w_qkv^T)        [bf16 out]
  gemm_bn<false><<<dim3(16, 8, 16), 256, 0, stream>>>(
      x, w_qkv, g_qkv, b_qkv, m_qkv, v_qkv, qkv, nullptr, 256, 512);
  // 2. att = attention(q, k, v)     [MFMA flash, f32 out]
  attn_mfma_kernel<<<dim3(16, 8, 16), 256, 0, stream>>>(qkv, att);
  // 3. att += BN(depthwise3x3(v))
  conv_bn_add_center<<<dim3(4, 256, 16), 256, 0, stream>>>(
      qkv, att, w_pos, g_pos, b_pos, m_pos, v_pos);
  // 4. out = BN(att @ w_proj^T)     [f32 out]
  gemm_bn<true><<<dim3(16, 4, 16), 256, 0, stream>>>(
      att, w_proj, g_proj, b_proj, m_proj, v_proj, nullptr,
      (float*)d_out, 256, 256);
}

// Round 3
// 187.649 us; speedup vs baseline: 1.2375x; 1.2375x over previous
//
#include <hip/hip_runtime.h>

typedef short v8s __attribute__((ext_vector_type(8)));
typedef float v4f __attribute__((ext_vector_type(4)));
typedef unsigned short u16;

#define NPIX 1024
#define EPS 1e-5f

__device__ __forceinline__ float bf2f(u16 u){
  return __uint_as_float(((unsigned)u) << 16);
}
__device__ __forceinline__ u16 f2bf(float f){
  unsigned b = __float_as_uint(f);
  b += 0x7FFF + ((b >> 16) & 1);   // RNE
  return (u16)(b >> 16);
}
// pack two f32 -> two bf16 in one VALU op (RNE, same bits as f2bf)
__device__ __forceinline__ unsigned cvtpk(float lo, float hi){
  unsigned r;
  asm("v_cvt_pk_bf16_f32 %0, %1, %2" : "=v"(r) : "v"(lo), "v"(hi));
  return r;
}
// native v_exp_f32 (2^x), bypassing OCML's checked exp2f path
__device__ __forceinline__ float exp2n(float x){
#if __has_builtin(__builtin_amdgcn_exp2f)
  return __builtin_amdgcn_exp2f(x);
#else
  float r; asm("v_exp_f32 %0, %1" : "=v"(r) : "v"(x)); return r;
#endif
}

// ---------------------------------------------------------------------------
// Plain-bf16 GEMM+BN: dst = BN(src @ W^T); src f32 (B,Cin,1024), W f32.
// Staging converts f32->bf16 via v_cvt_pk_bf16_f32 (1 op / 2 elems).
// grid: (16, Cout/64, B), block 256 (4 waves).
// ---------------------------------------------------------------------------
template<bool OUT_F32>
__global__ __launch_bounds__(256) void gemm_bn(
    const float* __restrict__ src, const float* __restrict__ W,
    const float* __restrict__ gam, const float* __restrict__ bet,
    const float* __restrict__ mu,  const float* __restrict__ var,
    u16* __restrict__ bout, float* __restrict__ fout, int Cin, int Cout)
{
  const int n0 = blockIdx.x * 64;
  const int o0 = blockIdx.y * 64;
  const int b  = blockIdx.z;
  const int tid = threadIdx.x;
  const int w = tid >> 6, lane = tid & 63, col = lane & 15, quad = lane >> 4;

  __shared__ u16 Alds[64 * 40];   // [m][k], stride 40 (80B rows, 16B aligned)
  __shared__ u16 Blds[32 * 68];   // [k][n], stride 68 (2-way u16 reads = free)

  v4f acc[4];
#pragma unroll
  for (int i = 0; i < 4; i++) acc[i] = (v4f){0.f, 0.f, 0.f, 0.f};

  const int arow = tid >> 2, acs = (tid & 3) * 8;   // A staging: 64x32
  const int brow = tid >> 3, bns = (tid & 7) * 8;   // B staging: 32x64

  for (int k0 = 0; k0 < Cin; k0 += 32) {
    // issue global loads before the barrier (latency overlaps barrier wait)
    const float* pa = W + (size_t)(o0 + arow) * Cin + k0 + acs;
    float4 a0 = ((const float4*)pa)[0];
    float4 a1 = ((const float4*)pa)[1];
    const float* pb = src + ((size_t)b * Cin + k0 + brow) * NPIX + n0 + bns;
    float4 b0 = ((const float4*)pb)[0];
    float4 b1 = ((const float4*)pb)[1];

    __syncthreads();
    {   // A tile: W rows f32 -> bf16 (packed converts)
      uint4 pk;
      pk.x = cvtpk(a0.x, a0.y);
      pk.y = cvtpk(a0.z, a0.w);
      pk.z = cvtpk(a1.x, a1.y);
      pk.w = cvtpk(a1.z, a1.w);
      *(uint4*)(&Alds[arow * 40 + acs]) = pk;   // 16B aligned (80B rows)
    }
    {   // B tile: src rows f32 -> bf16 (packed converts)
      uint2 lo, hi;
      lo.x = cvtpk(b0.x, b0.y);
      lo.y = cvtpk(b0.z, b0.w);
      hi.x = cvtpk(b1.x, b1.y);
      hi.y = cvtpk(b1.z, b1.w);
      *(uint2*)(&Blds[brow * 68 + bns])     = lo;  // 8B aligned (136B rows)
      *(uint2*)(&Blds[brow * 68 + bns + 4]) = hi;
    }
    __syncthreads();

    v8s bf;
#pragma unroll
    for (int jj = 0; jj < 8; jj++)
      bf[jj] = (short)Blds[(quad * 8 + jj) * 68 + w * 16 + col];
#pragma unroll
    for (int mt = 0; mt < 4; mt++) {
      v8s af = *(const v8s*)(&Alds[(mt * 16 + col) * 40 + quad * 8]);
      acc[mt] = __builtin_amdgcn_mfma_f32_16x16x32_bf16(af, bf, acc[mt], 0, 0, 0);
    }
  }

  const int n = n0 + w * 16 + col;
#pragma unroll
  for (int mt = 0; mt < 4; mt++) {
#pragma unroll
    for (int r = 0; r < 4; r++) {
      int o = o0 + mt * 16 + quad * 4 + r;
      float inv = rsqrtf(var[o] + EPS) * gam[o];
      float val = acc[mt][r] * inv + (bet[o] - mu[o] * inv);
      size_t idx = (size_t)(b * Cout + o) * NPIX + n;
      if (OUT_F32) fout[idx] = val;
      else         bout[idx] = f2bf(val);
    }
  }
}

// ---------------------------------------------------------------------------
// MFMA flash attention, no-max softmax (scores bounded), all-bf16 qkv.
// Swapped QK^T (mfma(K,Q)): each lane holds 4 consecutive keys of ONE query
// -> P-store is 2 cvt_pk + one 8B ds_write; single lsum accumulator.
// V staged in LDS (round-1 global-per-fragment V was latency-bound: -40%).
// Staging loads issued BEFORE the first barrier (latency under barrier wait).
// exp2-direct: Q pre-scaled by SCALE*log2(e); native v_exp_f32.
// grid: (16 q-tiles, 8 heads, 16 batch), block 256 (4 waves, 16 q/wave).
// ---------------------------------------------------------------------------
__global__ __launch_bounds__(256) void attn_mfma_kernel(
    const u16* __restrict__ qkv, float* __restrict__ att)
{
  const int qt = blockIdx.x, h = blockIdx.y, b = blockIdx.z;
  const int tid = threadIdx.x, w = tid >> 6, lane = tid & 63;
  const int col = lane & 15, quad = lane >> 4;
  const u16* base = qkv + (size_t)(b * 512 + h * 64) * NPIX;

  __shared__ u16 Kt[64 * 24];      // [j][k] transposed, stride 24
  __shared__ u16 Vl[32 * 72];      // [d][j], stride 72
  __shared__ u16 Pl[4][16 * 72];   // per-wave P round-trip, [query][j]

  const int q0 = qt * 64 + w * 16;

  // Q B-fragment (loop-invariant): B[n=q=col][k=quad*8+jj], k>=16 zero.
  // Scale = SCALE * log2(e) so scores feed exp2 directly.
  v8s qf = (v8s){0, 0, 0, 0, 0, 0, 0, 0};
  if (quad < 2) {
#pragma unroll
    for (int jj = 0; jj < 8; jj++) {
      int k = quad * 8 + jj;
      qf[jj] = (short)f2bf(bf2f(base[(size_t)k * NPIX + q0 + col])
                           * 0.36067376022224085f);
    }
  }

  float lsum = 0.f;
  v4f o_acc[2];
  o_acc[0] = (v4f){0, 0, 0, 0};
  o_acc[1] = (v4f){0, 0, 0, 0};

  const int kk4 = w * 4;                         // wave w stages k rows w*4..+3
  const int vd = tid >> 3, vjs = (tid & 7) * 8;  // V staging

  for (int j0 = 0; j0 < 1024; j0 += 64) {
    // issue staging loads into registers BEFORE the barrier
    ushort4 t;
    t.x = base[(size_t)(16 + kk4 + 0) * NPIX + j0 + lane];
    t.y = base[(size_t)(16 + kk4 + 1) * NPIX + j0 + lane];
    t.z = base[(size_t)(16 + kk4 + 2) * NPIX + j0 + lane];
    t.w = base[(size_t)(16 + kk4 + 3) * NPIX + j0 + lane];
    uint4 vt = *(const uint4*)(base + (size_t)(32 + vd) * NPIX + j0 + vjs);

    __syncthreads();
    *(ushort4*)(&Kt[lane * 24 + kk4]) = t;   // K transposed: Kt[j][k]
    *(uint4*)(&Vl[vd * 72 + vjs]) = vt;      // V: Vl[d][j]
    __syncthreads();

    // scores + exp2 + packed P-store.
    // s = mfma(K, Q): D[m=key][n=query] -> row=quad*4+r is key, col is query.
#pragma unroll
    for (int jt = 0; jt < 4; jt++) {
      v8s kf = (v8s){0, 0, 0, 0, 0, 0, 0, 0};
      if (quad < 2)
        kf = *(const v8s*)(&Kt[(jt * 16 + col) * 24 + quad * 8]);
      v4f z = (v4f){0, 0, 0, 0};
      v4f s = __builtin_amdgcn_mfma_f32_16x16x32_bf16(kf, qf, z, 0, 0, 0);
      float p0 = exp2n(s[0]);
      float p1 = exp2n(s[1]);
      float p2 = exp2n(s[2]);
      float p3 = exp2n(s[3]);
      lsum += (p0 + p1) + (p2 + p3);
      uint2 pk;
      pk.x = cvtpk(p0, p1);
      pk.y = cvtpk(p2, p3);
      // Pl[q=col][j = jt*16 + quad*4 .. +3]: 8B store, 2-way banks (free)
      *(uint2*)(&Pl[w][col * 72 + jt * 16 + quad * 4]) = pk;
    }

    // PV: D[m=query][n=d]; pf and vf from LDS (b128 reads).
#pragma unroll
    for (int T = 0; T < 2; T++) {
      v8s pf = *(const v8s*)(&Pl[w][col * 72 + T * 32 + quad * 8]);
#pragma unroll
      for (int dt = 0; dt < 2; dt++) {
        v8s vf = *(const v8s*)(&Vl[(dt * 16 + col) * 72 + T * 32 + quad * 8]);
        o_acc[dt] = __builtin_amdgcn_mfma_f32_16x16x32_bf16(pf, vf, o_acc[dt], 0, 0, 0);
      }
    }
  }

  // epilogue: cross-quad row-sum (each lane owns query q=col), then fetch
  // the sums for q=quad*4+r to match the o_acc D-layout, normalize, store.
  lsum += __shfl_xor(lsum, 16);
  lsum += __shfl_xor(lsum, 32);
  float ls[4];
#pragma unroll
  for (int r = 0; r < 4; r++) ls[r] = __shfl(lsum, quad * 4 + r);
#pragma unroll
  for (int dt = 0; dt < 2; dt++) {
    float4 pack;
    pack.x = o_acc[dt][0] * (1.f / ls[0]);
    pack.y = o_acc[dt][1] * (1.f / ls[1]);
    pack.z = o_acc[dt][2] * (1.f / ls[2]);
    pack.w = o_acc[dt][3] * (1.f / ls[3]);
    *(float4*)(&att[(size_t)(b * 256 + h * 32 + dt * 16 + col) * NPIX +
                    q0 + quad * 4]) = pack;
  }
}

// ---------------------------------------------------------------------------
// Depthwise 3x3 centered unflipped + BN; att(f32) += BN(conv(v)).
// grid: (4, 256, 16), block 256.
// ---------------------------------------------------------------------------
__global__ __launch_bounds__(256) void conv_bn_add_center(
    const u16* __restrict__ qkv, float* __restrict__ att,
    const float* __restrict__ wpos,
    const float* __restrict__ gam, const float* __restrict__ bet,
    const float* __restrict__ mu,  const float* __restrict__ var)
{
  const int c = blockIdx.y, b = blockIdx.z;
  const int p = blockIdx.x * 256 + threadIdx.x;
  const int y = p >> 5, x = p & 31;
  const u16* v = qkv + (size_t)(b * 512 + (c >> 5) * 64 + 32 + (c & 31)) * NPIX;

  float accv = 0.f;
#pragma unroll
  for (int ky = 0; ky < 3; ky++) {
    int yy = y + ky - 1;
    if (yy < 0 || yy > 31) continue;
#pragma unroll
    for (int kx = 0; kx < 3; kx++) {
      int xx = x + kx - 1;
      if (xx < 0 || xx > 31) continue;
      accv += bf2f(v[yy * 32 + xx]) * wpos[c * 9 + ky * 3 + kx];
    }
  }
  float inv = rsqrtf(var[c] + EPS) * gam[c];
  float add = bet[c] - mu[c] * inv;
  size_t idx = (size_t)(b * 256 + c) * NPIX + p;
  att[idx] = accv * inv + add + att[idx];
}

// ---------------------------------------------------------------------------
extern "C" void kernel_launch(void* const* d_in, const int* in_sizes, int n_in,
                              void* d_out, int out_size, void* d_ws, size_t ws_size,
                              hipStream_t stream)
{
  (void)in_sizes; (void)n_in; (void)out_size; (void)ws_size;
  const float* x      = (const float*)d_in[0];
  const float* w_qkv  = (const float*)d_in[1];
  const float* g_qkv  = (const float*)d_in[2];
  const float* b_qkv  = (const float*)d_in[3];
  const float* m_qkv  = (const float*)d_in[4];
  const float* v_qkv  = (const float*)d_in[5];
  const float* w_pos  = (const float*)d_in[6];
  const float* g_pos  = (const float*)d_in[7];
  const float* b_pos  = (const float*)d_in[8];
  const float* m_pos  = (const float*)d_in[9];
  const float* v_pos  = (const float*)d_in[10];
  const float* w_proj = (const float*)d_in[11];
  const float* g_proj = (const float*)d_in[12];
  const float* b_proj = (const float*)d_in[13];
  const float* m_proj = (const float*)d_in[14];
  const float* v_proj = (const float*)d_in[15];

  // Buffer plan:
  //   qkv bf16 (16,512,1024): ws[0..16MB)
  //   att f32  (16,256,1024): x buffer (dead after gemm1; harness restores)
  u16*   qkv = (u16*)d_ws;
  float* att = (float*)d_in[0];

  // 1. qkv = BN(x @ w_qkv^T)        [bf16 out]
  gemm_bn<false><<<dim3(16, 8, 16), 256, 0, stream>>>(
      x, w_qkv, g_qkv, b_qkv, m_qkv, v_qkv, qkv, nullptr, 256, 512);
  // 2. att = attention(q, k, v)     [MFMA flash, f32 out]
  attn_mfma_kernel<<<dim3(16, 8, 16), 256, 0, stream>>>(qkv, att);
  // 3. att += BN(depthwise3x3(v))
  conv_bn_add_center<<<dim3(4, 256, 16), 256, 0, stream>>>(
      qkv, att, w_pos, g_pos, b_pos, m_pos, v_pos);
  // 4. out = BN(att @ w_proj^T)     [f32 out]
  gemm_bn<true><<<dim3(16, 4, 16), 256, 0, stream>>>(
      att, w_proj, g_proj, b_proj, m_proj, v_proj, nullptr,
      (float*)d_out, 256, 256);
}

// Round 5
// 184.463 us; speedup vs baseline: 1.2588x; 1.0173x over previous
//
#include <hip/hip_runtime.h>

typedef short v8s __attribute__((ext_vector_type(8)));
typedef float v4f __attribute__((ext_vector_type(4)));
typedef unsigned short u16;

#define NPIX 1024
#define EPS 1e-5f

__device__ __forceinline__ float bf2f(u16 u){
  return __uint_as_float(((unsigned)u) << 16);
}
__device__ __forceinline__ u16 f2bf(float f){
  unsigned b = __float_as_uint(f);
  b += 0x7FFF + ((b >> 16) & 1);   // RNE
  return (u16)(b >> 16);
}
// pack two f32 -> two bf16 in one VALU op (RNE, same bits as f2bf)
__device__ __forceinline__ unsigned cvtpk(float lo, float hi){
  unsigned r;
  asm("v_cvt_pk_bf16_f32 %0, %1, %2" : "=v"(r) : "v"(lo), "v"(hi));
  return r;
}
// native v_exp_f32 (2^x), bypassing OCML's checked exp2f path
__device__ __forceinline__ float exp2n(float x){
#if __has_builtin(__builtin_amdgcn_exp2f)
  return __builtin_amdgcn_exp2f(x);
#else
  float r; asm("v_exp_f32 %0, %1" : "=v"(r) : "v"(x)); return r;
#endif
}

// ---------------------------------------------------------------------------
// GEMM+BN, operand-swapped: dst = BN(src @ W^T).
//   A-operand = src (m = pixel), staged transposed [pixel][k] via gather.
//   B-operand = W   (n = o-chan), [o][k] row-major = contiguous k -> b128.
// D-layout: lane owns ONE o-channel x 4 consecutive pixels -> epilogue is
// 1 BN coeff set + 4 vector stores (was 16 sets + 16 scalar stores).
// Single-barrier double-buffered staging (write buf, barrier, compute).
// grid: (16, Cout/64, B), block 256 (4 waves).
// ---------------------------------------------------------------------------
template<bool OUT_F32>
__global__ __launch_bounds__(256) void gemm_bn(
    const float* __restrict__ src, const float* __restrict__ W,
    const float* __restrict__ gam, const float* __restrict__ bet,
    const float* __restrict__ mu,  const float* __restrict__ var,
    u16* __restrict__ bout, float* __restrict__ fout, int Cin, int Cout)
{
  const int n0 = blockIdx.x * 64;   // pixel tile
  const int o0 = blockIdx.y * 64;   // out-channel tile
  const int b  = blockIdx.z;
  const int tid = threadIdx.x;
  const int w = tid >> 6, lane = tid & 63, col = lane & 15, quad = lane >> 4;

  __shared__ u16 Wl[2][64 * 40];   // [o][k], stride 40 (80B rows, 16B-aligned)
  __shared__ u16 Sr[2][64 * 40];   // [pixel][k] (transposed src tile)

  // one BN coefficient set per lane (its single output channel)
  const int o = o0 + w * 16 + col;
  const float inv = rsqrtf(var[o] + EPS) * gam[o];
  const float add = bet[o] - mu[o] * inv;

  v4f acc[4];
#pragma unroll
  for (int i = 0; i < 4; i++) acc[i] = (v4f){0.f, 0.f, 0.f, 0.f};

  // staging assignments
  const int so = tid >> 2, sks = (tid & 3) * 8;   // W: 64 o-rows x 4 k-slots
  const int sp = tid & 63, skg = (tid >> 6) * 8;  // src: 64 pixels x 4 k-grps

  const float* wp = W + (size_t)(o0 + so) * Cin + sks;
  const float* sb = src + (size_t)b * Cin * NPIX + n0 + sp;

  // prologue: tile 0 into regs
  float4 wa = ((const float4*)wp)[0];
  float4 wb = ((const float4*)wp)[1];
  float sv[8];
#pragma unroll
  for (int i = 0; i < 8; i++) sv[i] = sb[(size_t)(skg + i) * NPIX];

  const int nt = Cin >> 5;
  int cur = 0;
  for (int t = 0; t < nt; ++t) {
    {   // W tile -> LDS (contiguous k, no transpose)
      uint4 pk;
      pk.x = cvtpk(wa.x, wa.y);
      pk.y = cvtpk(wa.z, wa.w);
      pk.z = cvtpk(wb.x, wb.y);
      pk.w = cvtpk(wb.z, wb.w);
      *(uint4*)(&Wl[cur][so * 40 + sks]) = pk;
    }
    {   // src tile -> LDS transposed [pixel][k]
      uint4 pk;
      pk.x = cvtpk(sv[0], sv[1]);
      pk.y = cvtpk(sv[2], sv[3]);
      pk.z = cvtpk(sv[4], sv[5]);
      pk.w = cvtpk(sv[6], sv[7]);
      *(uint4*)(&Sr[cur][sp * 40 + skg]) = pk;
    }
    if (t + 1 < nt) {   // issue next tile's loads (hidden under compute)
      const float* wpn = wp + (t + 1) * 32;
      wa = ((const float4*)wpn)[0];
      wb = ((const float4*)wpn)[1];
      const float* sbn = sb + (size_t)((t + 1) * 32 + skg) * NPIX;
#pragma unroll
      for (int i = 0; i < 8; i++) sv[i] = sbn[(size_t)i * NPIX];
    }
    __syncthreads();

    v8s bfrag = *(const v8s*)(&Wl[cur][(w * 16 + col) * 40 + quad * 8]);
#pragma unroll
    for (int mt = 0; mt < 4; mt++) {
      v8s af = *(const v8s*)(&Sr[cur][(mt * 16 + col) * 40 + quad * 8]);
      acc[mt] = __builtin_amdgcn_mfma_f32_16x16x32_bf16(af, bfrag, acc[mt], 0, 0, 0);
    }
    cur ^= 1;
  }

  // epilogue: pixel = n0 + mt*16 + quad*4 + r (contiguous in r)
  const size_t orow = (size_t)(b * Cout + o) * NPIX + n0 + quad * 4;
#pragma unroll
  for (int mt = 0; mt < 4; mt++) {
    float v0 = acc[mt][0] * inv + add;
    float v1 = acc[mt][1] * inv + add;
    float v2 = acc[mt][2] * inv + add;
    float v3 = acc[mt][3] * inv + add;
    if (OUT_F32) {
      *(float4*)(&fout[orow + mt * 16]) = make_float4(v0, v1, v2, v3);
    } else {
      uint2 pk;
      pk.x = cvtpk(v0, v1);
      pk.y = cvtpk(v2, v3);
      *(uint2*)(&bout[orow + mt * 16]) = pk;
    }
  }
}

// ---------------------------------------------------------------------------
// MFMA flash attention, no-max softmax (scores bounded), all-bf16 qkv.
// Swapped QK^T (mfma(K,Q)) + packed P-store; single-barrier double-buffered
// K/V staging (same scheme as gemm_bn). Pl stride 72: each query row spans
// 64 j-entries (round-4's stride-40 overlapped rows -> corruption).
// exp2-direct with native v_exp_f32.
// grid: (16 q-tiles, 8 heads, 16 batch), block 256 (4 waves, 16 q/wave).
// ---------------------------------------------------------------------------
__global__ __launch_bounds__(256) void attn_mfma_kernel(
    const u16* __restrict__ qkv, float* __restrict__ att)
{
  const int qt = blockIdx.x, h = blockIdx.y, b = blockIdx.z;
  const int tid = threadIdx.x, w = tid >> 6, lane = tid & 63;
  const int col = lane & 15, quad = lane >> 4;
  const u16* base = qkv + (size_t)(b * 512 + h * 64) * NPIX;

  __shared__ u16 Kt[2][64 * 24];   // [j][k] transposed, stride 24
  __shared__ u16 Vl[2][32 * 72];   // [d][j], stride 72
  __shared__ u16 Pl[4][16 * 72];   // per-wave P round-trip, [query][j], 64 j/row

  const int q0 = qt * 64 + w * 16;

  // Q B-fragment (loop-invariant): B[n=q=col][k=quad*8+jj], k>=16 zero.
  // Scale = SCALE * log2(e) so scores feed exp2 directly.
  v8s qf = (v8s){0, 0, 0, 0, 0, 0, 0, 0};
  if (quad < 2) {
#pragma unroll
    for (int jj = 0; jj < 8; jj++) {
      int k = quad * 8 + jj;
      qf[jj] = (short)f2bf(bf2f(base[(size_t)k * NPIX + q0 + col])
                           * 0.36067376022224085f);
    }
  }

  float lsum = 0.f;
  v4f o_acc[2];
  o_acc[0] = (v4f){0, 0, 0, 0};
  o_acc[1] = (v4f){0, 0, 0, 0};

  const int kk4 = w * 4;                         // wave w stages k rows w*4..+3
  const int vd = tid >> 3, vjs = (tid & 7) * 8;  // V staging

  // prologue: tile 0 into regs
  ushort4 kr;
  kr.x = base[(size_t)(16 + kk4 + 0) * NPIX + lane];
  kr.y = base[(size_t)(16 + kk4 + 1) * NPIX + lane];
  kr.z = base[(size_t)(16 + kk4 + 2) * NPIX + lane];
  kr.w = base[(size_t)(16 + kk4 + 3) * NPIX + lane];
  uint4 vr = *(const uint4*)(base + (size_t)(32 + vd) * NPIX + vjs);

  int cur = 0;
  for (int t = 0; t < 16; ++t) {
    *(ushort4*)(&Kt[cur][lane * 24 + kk4]) = kr;   // K transposed: Kt[j][k]
    *(uint4*)(&Vl[cur][vd * 72 + vjs]) = vr;       // V: Vl[d][j]
    if (t < 15) {   // issue next tile's loads (hidden under compute)
      const int j0n = (t + 1) * 64;
      kr.x = base[(size_t)(16 + kk4 + 0) * NPIX + j0n + lane];
      kr.y = base[(size_t)(16 + kk4 + 1) * NPIX + j0n + lane];
      kr.z = base[(size_t)(16 + kk4 + 2) * NPIX + j0n + lane];
      kr.w = base[(size_t)(16 + kk4 + 3) * NPIX + j0n + lane];
      vr = *(const uint4*)(base + (size_t)(32 + vd) * NPIX + j0n + vjs);
    }
    __syncthreads();

    // scores + exp2 + packed P-store.
    // s = mfma(K, Q): D[m=key][n=query] -> row=quad*4+r is key, col is query.
#pragma unroll
    for (int jt = 0; jt < 4; jt++) {
      v8s kf = (v8s){0, 0, 0, 0, 0, 0, 0, 0};
      if (quad < 2)
        kf = *(const v8s*)(&Kt[cur][(jt * 16 + col) * 24 + quad * 8]);
      v4f z = (v4f){0, 0, 0, 0};
      v4f s = __builtin_amdgcn_mfma_f32_16x16x32_bf16(kf, qf, z, 0, 0, 0);
      float p0 = exp2n(s[0]);
      float p1 = exp2n(s[1]);
      float p2 = exp2n(s[2]);
      float p3 = exp2n(s[3]);
      lsum += (p0 + p1) + (p2 + p3);
      uint2 pk;
      pk.x = cvtpk(p0, p1);
      pk.y = cvtpk(p2, p3);
      // Pl[q=col][j = jt*16 + quad*4 .. +3]: 8B store
      *(uint2*)(&Pl[w][col * 72 + jt * 16 + quad * 4]) = pk;
    }

    // PV: D[m=query][n=d]; pf and vf from LDS (b128 reads).
#pragma unroll
    for (int T = 0; T < 2; T++) {
      v8s pf = *(const v8s*)(&Pl[w][col * 72 + T * 32 + quad * 8]);
#pragma unroll
      for (int dt = 0; dt < 2; dt++) {
        v8s vf = *(const v8s*)(&Vl[cur][(dt * 16 + col) * 72 + T * 32 + quad * 8]);
        o_acc[dt] = __builtin_amdgcn_mfma_f32_16x16x32_bf16(pf, vf, o_acc[dt], 0, 0, 0);
      }
    }
    cur ^= 1;
  }

  // epilogue: cross-quad row-sum (each lane owns query q=col), then fetch
  // the sums for q=quad*4+r to match the o_acc D-layout, normalize, store.
  lsum += __shfl_xor(lsum, 16);
  lsum += __shfl_xor(lsum, 32);
  float ls[4];
#pragma unroll
  for (int r = 0; r < 4; r++) ls[r] = __shfl(lsum, quad * 4 + r);
#pragma unroll
  for (int dt = 0; dt < 2; dt++) {
    float4 pack;
    pack.x = o_acc[dt][0] * (1.f / ls[0]);
    pack.y = o_acc[dt][1] * (1.f / ls[1]);
    pack.z = o_acc[dt][2] * (1.f / ls[2]);
    pack.w = o_acc[dt][3] * (1.f / ls[3]);
    *(float4*)(&att[(size_t)(b * 256 + h * 32 + dt * 16 + col) * NPIX +
                    q0 + quad * 4]) = pack;
  }
}

// ---------------------------------------------------------------------------
// Depthwise 3x3 centered unflipped + BN; att(f32) += BN(conv(v)).
// grid: (4, 256, 16), block 256.
// ---------------------------------------------------------------------------
__global__ __launch_bounds__(256) void conv_bn_add_center(
    const u16* __restrict__ qkv, float* __restrict__ att,
    const float* __restrict__ wpos,
    const float* __restrict__ gam, const float* __restrict__ bet,
    const float* __restrict__ mu,  const float* __restrict__ var)
{
  const int c = blockIdx.y, b = blockIdx.z;
  const int p = blockIdx.x * 256 + threadIdx.x;
  const int y = p >> 5, x = p & 31;
  const u16* v = qkv + (size_t)(b * 512 + (c >> 5) * 64 + 32 + (c & 31)) * NPIX;

  float accv = 0.f;
#pragma unroll
  for (int ky = 0; ky < 3; ky++) {
    int yy = y + ky - 1;
    if (yy < 0 || yy > 31) continue;
#pragma unroll
    for (int kx = 0; kx < 3; kx++) {
      int xx = x + kx - 1;
      if (xx < 0 || xx > 31) continue;
      accv += bf2f(v[yy * 32 + xx]) * wpos[c * 9 + ky * 3 + kx];
    }
  }
  float inv = rsqrtf(var[c] + EPS) * gam[c];
  float add = bet[c] - mu[c] * inv;
  size_t idx = (size_t)(b * 256 + c) * NPIX + p;
  att[idx] = accv * inv + add + att[idx];
}

// ---------------------------------------------------------------------------
extern "C" void kernel_launch(void* const* d_in, const int* in_sizes, int n_in,
                              void* d_out, int out_size, void* d_ws, size_t ws_size,
                              hipStream_t stream)
{
  (void)in_sizes; (void)n_in; (void)out_size; (void)ws_size;
  const float* x      = (const float*)d_in[0];
  const float* w_qkv  = (const float*)d_in[1];
  const float* g_qkv  = (const float*)d_in[2];
  const float* b_qkv  = (const float*)d_in[3];
  const float* m_qkv  = (const float*)d_in[4];
  const float* v_qkv  = (const float*)d_in[5];
  const float* w_pos  = (const float*)d_in[6];
  const float* g_pos  = (const float*)d_in[7];
  const float* b_pos  = (const float*)d_in[8];
  const float* m_pos  = (const float*)d_in[9];
  const float* v_pos  = (const float*)d_in[10];
  const float* w_proj = (const float*)d_in[11];
  const float* g_proj = (const float*)d_in[12];
  const float* b_proj = (const float*)d_in[13];
  const float* m_proj = (const float*)d_in[14];
  const float* v_proj = (const float*)d_in[15];

  // Buffer plan:
  //   qkv bf16 (16,512,1024): ws[0..16MB)
  //   att f32  (16,256,1024): x buffer (dead after gemm1; harness restores)
  u16*   qkv = (u16*)d_ws;
  float* att = (float*)d_in[0];

  // 1. qkv = BN(x @ w_qkv^T)        [bf16 out]
  gemm_bn<false><<<dim3(16, 8, 16), 256, 0, stream>>>(
      x, w_qkv, g_qkv, b_qkv, m_qkv, v_qkv, qkv, nullptr, 256, 512);
  // 2. att = attention(q, k, v)     [MFMA flash, f32 out]
  attn_mfma_kernel<<<dim3(16, 8, 16), 256, 0, stream>>>(qkv, att);
  // 3. att += BN(depthwise3x3(v))
  conv_bn_add_center<<<dim3(4, 256, 16), 256, 0, stream>>>(
      qkv, att, w_pos, g_pos, b_pos, m_pos, v_pos);
  // 4. out = BN(att @ w_proj^T)     [f32 out]
  gemm_bn<true><<<dim3(16, 4, 16), 256, 0, stream>>>(
      att, w_proj, g_proj, b_proj, m_proj, v_proj, nullptr,
      (float*)d_out, 256, 256);
}

// Round 6
// 160.351 us; speedup vs baseline: 1.4481x; 1.1504x over previous
//
#include <hip/hip_runtime.h>

typedef short v8s __attribute__((ext_vector_type(8)));
typedef float v4f __attribute__((ext_vector_type(4)));
typedef unsigned short u16;

#define NPIX 1024
#define EPS 1e-5f

__device__ __forceinline__ float bf2f(u16 u){
  return __uint_as_float(((unsigned)u) << 16);
}
__device__ __forceinline__ u16 f2bf(float f){
  unsigned b = __float_as_uint(f);
  b += 0x7FFF + ((b >> 16) & 1);   // RNE
  return (u16)(b >> 16);
}
// pack two f32 -> two bf16 in one VALU op (RNE, same bits as f2bf)
__device__ __forceinline__ unsigned cvtpk(float lo, float hi){
  unsigned r;
  asm("v_cvt_pk_bf16_f32 %0, %1, %2" : "=v"(r) : "v"(lo), "v"(hi));
  return r;
}
// native v_exp_f32 (2^x), bypassing OCML's checked exp2f path
__device__ __forceinline__ float exp2n(float x){
#if __has_builtin(__builtin_amdgcn_exp2f)
  return __builtin_amdgcn_exp2f(x);
#else
  float r; asm("v_exp_f32 %0, %1" : "=v"(r) : "v"(x)); return r;
#endif
}

// ---------------------------------------------------------------------------
// GEMM+BN, operand-swapped: dst = BN(src @ W^T).
//   A-operand = src (m = pixel), staged transposed [pixel][k] via gather.
//   B-operand = W   (n = o-chan), [o][k] row-major = contiguous k -> b128.
// D-layout: lane owns ONE o-channel x 4 consecutive pixels -> epilogue is
// 1 BN coeff set + 4 vector stores. Single-barrier double-buffered staging.
// grid: (16, Cout/64, B), block 256 (4 waves).
// ---------------------------------------------------------------------------
template<bool OUT_F32>
__global__ __launch_bounds__(256) void gemm_bn(
    const float* __restrict__ src, const float* __restrict__ W,
    const float* __restrict__ gam, const float* __restrict__ bet,
    const float* __restrict__ mu,  const float* __restrict__ var,
    u16* __restrict__ bout, float* __restrict__ fout, int Cin, int Cout)
{
  const int n0 = blockIdx.x * 64;   // pixel tile
  const int o0 = blockIdx.y * 64;   // out-channel tile
  const int b  = blockIdx.z;
  const int tid = threadIdx.x;
  const int w = tid >> 6, lane = tid & 63, col = lane & 15, quad = lane >> 4;

  __shared__ u16 Wl[2][64 * 40];   // [o][k], stride 40 (80B rows, 16B-aligned)
  __shared__ u16 Sr[2][64 * 40];   // [pixel][k] (transposed src tile)

  // one BN coefficient set per lane (its single output channel)
  const int o = o0 + w * 16 + col;
  const float inv = rsqrtf(var[o] + EPS) * gam[o];
  const float add = bet[o] - mu[o] * inv;

  v4f acc[4];
#pragma unroll
  for (int i = 0; i < 4; i++) acc[i] = (v4f){0.f, 0.f, 0.f, 0.f};

  // staging assignments
  const int so = tid >> 2, sks = (tid & 3) * 8;   // W: 64 o-rows x 4 k-slots
  const int sp = tid & 63, skg = (tid >> 6) * 8;  // src: 64 pixels x 4 k-grps

  const float* wp = W + (size_t)(o0 + so) * Cin + sks;
  const float* sb = src + (size_t)b * Cin * NPIX + n0 + sp;

  // prologue: tile 0 into regs
  float4 wa = ((const float4*)wp)[0];
  float4 wb = ((const float4*)wp)[1];
  float sv[8];
#pragma unroll
  for (int i = 0; i < 8; i++) sv[i] = sb[(size_t)(skg + i) * NPIX];

  const int nt = Cin >> 5;
  int cur = 0;
  for (int t = 0; t < nt; ++t) {
    {   // W tile -> LDS (contiguous k, no transpose)
      uint4 pk;
      pk.x = cvtpk(wa.x, wa.y);
      pk.y = cvtpk(wa.z, wa.w);
      pk.z = cvtpk(wb.x, wb.y);
      pk.w = cvtpk(wb.z, wb.w);
      *(uint4*)(&Wl[cur][so * 40 + sks]) = pk;
    }
    {   // src tile -> LDS transposed [pixel][k]
      uint4 pk;
      pk.x = cvtpk(sv[0], sv[1]);
      pk.y = cvtpk(sv[2], sv[3]);
      pk.z = cvtpk(sv[4], sv[5]);
      pk.w = cvtpk(sv[6], sv[7]);
      *(uint4*)(&Sr[cur][sp * 40 + skg]) = pk;
    }
    if (t + 1 < nt) {   // issue next tile's loads (hidden under compute)
      const float* wpn = wp + (t + 1) * 32;
      wa = ((const float4*)wpn)[0];
      wb = ((const float4*)wpn)[1];
      const float* sbn = sb + (size_t)((t + 1) * 32 + skg) * NPIX;
#pragma unroll
      for (int i = 0; i < 8; i++) sv[i] = sbn[(size_t)i * NPIX];
    }
    __syncthreads();

    v8s bfrag = *(const v8s*)(&Wl[cur][(w * 16 + col) * 40 + quad * 8]);
#pragma unroll
    for (int mt = 0; mt < 4; mt++) {
      v8s af = *(const v8s*)(&Sr[cur][(mt * 16 + col) * 40 + quad * 8]);
      acc[mt] = __builtin_amdgcn_mfma_f32_16x16x32_bf16(af, bfrag, acc[mt], 0, 0, 0);
    }
    cur ^= 1;
  }

  // epilogue: pixel = n0 + mt*16 + quad*4 + r (contiguous in r)
  const size_t orow = (size_t)(b * Cout + o) * NPIX + n0 + quad * 4;
#pragma unroll
  for (int mt = 0; mt < 4; mt++) {
    float v0 = acc[mt][0] * inv + add;
    float v1 = acc[mt][1] * inv + add;
    float v2 = acc[mt][2] * inv + add;
    float v3 = acc[mt][3] * inv + add;
    if (OUT_F32) {
      *(float4*)(&fout[orow + mt * 16]) = make_float4(v0, v1, v2, v3);
    } else {
      uint2 pk;
      pk.x = cvtpk(v0, v1);
      pk.y = cvtpk(v2, v3);
      *(uint2*)(&bout[orow + mt * 16]) = pk;
    }
  }
}

// ---------------------------------------------------------------------------
// MFMA flash attention + FUSED depthwise-3x3+BN epilogue.
// Main loop identical to the round-5 verified kernel (swapped QK^T, packed
// P-store, single-barrier dbuf K/V staging, exp2-direct).
// Epilogue: each lane owns channel h*32+dt*16+col at pixels q0+quad*4..+3;
// the needed v rows (32+dt*16+col of this head's panel) were just streamed
// -> L2-warm. conv = 3 rows x 6 taps, zero-padded via clamps. This deletes
// the conv_bn_add_center dispatch and its 33.6MB att read-modify-write.
// grid: (16 q-tiles, 8 heads, 16 batch), block 256 (4 waves, 16 q/wave).
// ---------------------------------------------------------------------------
__global__ __launch_bounds__(256) void attn_mfma_kernel(
    const u16* __restrict__ qkv, float* __restrict__ att,
    const float* __restrict__ wpos,
    const float* __restrict__ g_pos, const float* __restrict__ b_pos,
    const float* __restrict__ m_pos, const float* __restrict__ v_pos)
{
  const int qt = blockIdx.x, h = blockIdx.y, b = blockIdx.z;
  const int tid = threadIdx.x, w = tid >> 6, lane = tid & 63;
  const int col = lane & 15, quad = lane >> 4;
  const u16* base = qkv + (size_t)(b * 512 + h * 64) * NPIX;

  __shared__ u16 Kt[2][64 * 24];   // [j][k] transposed, stride 24
  __shared__ u16 Vl[2][32 * 72];   // [d][j], stride 72
  __shared__ u16 Pl[4][16 * 72];   // per-wave P round-trip, [query][j], 64 j/row

  const int q0 = qt * 64 + w * 16;

  // Q B-fragment (loop-invariant): B[n=q=col][k=quad*8+jj], k>=16 zero.
  // Scale = SCALE * log2(e) so scores feed exp2 directly.
  v8s qf = (v8s){0, 0, 0, 0, 0, 0, 0, 0};
  if (quad < 2) {
#pragma unroll
    for (int jj = 0; jj < 8; jj++) {
      int k = quad * 8 + jj;
      qf[jj] = (short)f2bf(bf2f(base[(size_t)k * NPIX + q0 + col])
                           * 0.36067376022224085f);
    }
  }

  float lsum = 0.f;
  v4f o_acc[2];
  o_acc[0] = (v4f){0, 0, 0, 0};
  o_acc[1] = (v4f){0, 0, 0, 0};

  const int kk4 = w * 4;                         // wave w stages k rows w*4..+3
  const int vd = tid >> 3, vjs = (tid & 7) * 8;  // V staging

  // prologue: tile 0 into regs
  ushort4 kr;
  kr.x = base[(size_t)(16 + kk4 + 0) * NPIX + lane];
  kr.y = base[(size_t)(16 + kk4 + 1) * NPIX + lane];
  kr.z = base[(size_t)(16 + kk4 + 2) * NPIX + lane];
  kr.w = base[(size_t)(16 + kk4 + 3) * NPIX + lane];
  uint4 vr = *(const uint4*)(base + (size_t)(32 + vd) * NPIX + vjs);

  int cur = 0;
  for (int t = 0; t < 16; ++t) {
    *(ushort4*)(&Kt[cur][lane * 24 + kk4]) = kr;   // K transposed: Kt[j][k]
    *(uint4*)(&Vl[cur][vd * 72 + vjs]) = vr;       // V: Vl[d][j]
    if (t < 15) {   // issue next tile's loads (hidden under compute)
      const int j0n = (t + 1) * 64;
      kr.x = base[(size_t)(16 + kk4 + 0) * NPIX + j0n + lane];
      kr.y = base[(size_t)(16 + kk4 + 1) * NPIX + j0n + lane];
      kr.z = base[(size_t)(16 + kk4 + 2) * NPIX + j0n + lane];
      kr.w = base[(size_t)(16 + kk4 + 3) * NPIX + j0n + lane];
      vr = *(const uint4*)(base + (size_t)(32 + vd) * NPIX + j0n + vjs);
    }
    __syncthreads();

    // scores + exp2 + packed P-store.
    // s = mfma(K, Q): D[m=key][n=query] -> row=quad*4+r is key, col is query.
#pragma unroll
    for (int jt = 0; jt < 4; jt++) {
      v8s kf = (v8s){0, 0, 0, 0, 0, 0, 0, 0};
      if (quad < 2)
        kf = *(const v8s*)(&Kt[cur][(jt * 16 + col) * 24 + quad * 8]);
      v4f z = (v4f){0, 0, 0, 0};
      v4f s = __builtin_amdgcn_mfma_f32_16x16x32_bf16(kf, qf, z, 0, 0, 0);
      float p0 = exp2n(s[0]);
      float p1 = exp2n(s[1]);
      float p2 = exp2n(s[2]);
      float p3 = exp2n(s[3]);
      lsum += (p0 + p1) + (p2 + p3);
      uint2 pk;
      pk.x = cvtpk(p0, p1);
      pk.y = cvtpk(p2, p3);
      // Pl[q=col][j = jt*16 + quad*4 .. +3]: 8B store
      *(uint2*)(&Pl[w][col * 72 + jt * 16 + quad * 4]) = pk;
    }

    // PV: D[m=query][n=d]; pf and vf from LDS (b128 reads).
#pragma unroll
    for (int T = 0; T < 2; T++) {
      v8s pf = *(const v8s*)(&Pl[w][col * 72 + T * 32 + quad * 8]);
#pragma unroll
      for (int dt = 0; dt < 2; dt++) {
        v8s vf = *(const v8s*)(&Vl[cur][(dt * 16 + col) * 72 + T * 32 + quad * 8]);
        o_acc[dt] = __builtin_amdgcn_mfma_f32_16x16x32_bf16(pf, vf, o_acc[dt], 0, 0, 0);
      }
    }
    cur ^= 1;
  }

  // ---- epilogue -----------------------------------------------------------
  // row-sums: each lane owns query q=col; fetch sums for q=quad*4+r.
  lsum += __shfl_xor(lsum, 16);
  lsum += __shfl_xor(lsum, 32);
  float ls[4];
#pragma unroll
  for (int r = 0; r < 4; r++) ls[r] = __shfl(lsum, quad * 4 + r);

  // fused depthwise-3x3 conv + BN for this lane's 2 channels x 4 pixels.
  // pixels p0..p0+3 lie in one image row (q0 mult of 16, quad*4+3 <= 15).
  const int p0 = q0 + quad * 4;
  const int y  = p0 >> 5, x0 = p0 & 31;

#pragma unroll
  for (int dt = 0; dt < 2; dt++) {
    const int cl = dt * 16 + col;            // channel within head (0..31)
    const int ca = h * 32 + cl;              // global att channel (0..255)
    const u16* vrow = base + (size_t)(32 + cl) * NPIX;
    const float* w9 = wpos + ca * 9;
    const float cinv = rsqrtf(v_pos[ca] + EPS) * g_pos[ca];
    const float cadd = b_pos[ca] - m_pos[ca] * cinv;

    float cv0 = 0.f, cv1 = 0.f, cv2 = 0.f, cv3 = 0.f;
#pragma unroll
    for (int ky = 0; ky < 3; ky++) {
      const int yy = y + ky - 1;
      if (yy < 0 || yy > 31) continue;       // zero-pad rows
      const u16* rp = vrow + yy * 32 + x0;
      const float w0 = w9[ky * 3 + 0];
      const float w1 = w9[ky * 3 + 1];
      const float w2 = w9[ky * 3 + 2];
      const float tm = (x0 >= 1)      ? bf2f(rp[-1]) : 0.f;   // zero-pad cols
      const float t0 = bf2f(rp[0]);
      const float t1 = bf2f(rp[1]);
      const float t2 = bf2f(rp[2]);
      const float t3 = bf2f(rp[3]);
      const float t4 = (x0 + 4 <= 31) ? bf2f(rp[4]) : 0.f;
      cv0 += tm * w0 + t0 * w1 + t1 * w2;
      cv1 += t0 * w0 + t1 * w1 + t2 * w2;
      cv2 += t1 * w0 + t2 * w1 + t3 * w2;
      cv3 += t2 * w0 + t3 * w1 + t4 * w2;
    }

    float4 pack;
    pack.x = o_acc[dt][0] * (1.f / ls[0]) + cv0 * cinv + cadd;
    pack.y = o_acc[dt][1] * (1.f / ls[1]) + cv1 * cinv + cadd;
    pack.z = o_acc[dt][2] * (1.f / ls[2]) + cv2 * cinv + cadd;
    pack.w = o_acc[dt][3] * (1.f / ls[3]) + cv3 * cinv + cadd;
    *(float4*)(&att[(size_t)(b * 256 + ca) * NPIX + p0]) = pack;
  }
}

// ---------------------------------------------------------------------------
extern "C" void kernel_launch(void* const* d_in, const int* in_sizes, int n_in,
                              void* d_out, int out_size, void* d_ws, size_t ws_size,
                              hipStream_t stream)
{
  (void)in_sizes; (void)n_in; (void)out_size; (void)ws_size;
  const float* x      = (const float*)d_in[0];
  const float* w_qkv  = (const float*)d_in[1];
  const float* g_qkv  = (const float*)d_in[2];
  const float* b_qkv  = (const float*)d_in[3];
  const float* m_qkv  = (const float*)d_in[4];
  const float* v_qkv  = (const float*)d_in[5];
  const float* w_pos  = (const float*)d_in[6];
  const float* g_pos  = (const float*)d_in[7];
  const float* b_pos  = (const float*)d_in[8];
  const float* m_pos  = (const float*)d_in[9];
  const float* v_pos  = (const float*)d_in[10];
  const float* w_proj = (const float*)d_in[11];
  const float* g_proj = (const float*)d_in[12];
  const float* b_proj = (const float*)d_in[13];
  const float* m_proj = (const float*)d_in[14];
  const float* v_proj = (const float*)d_in[15];

  // Buffer plan:
  //   qkv bf16 (16,512,1024): ws[0..16MB)
  //   att f32  (16,256,1024): x buffer (dead after gemm1; harness restores)
  u16*   qkv = (u16*)d_ws;
  float* att = (float*)d_in[0];

  // 1. qkv = BN(x @ w_qkv^T)        [bf16 out]
  gemm_bn<false><<<dim3(16, 8, 16), 256, 0, stream>>>(
      x, w_qkv, g_qkv, b_qkv, m_qkv, v_qkv, qkv, nullptr, 256, 512);
  // 2. att = attention(q,k,v) + BN(depthwise3x3(v))   [fused, f32 out]
  attn_mfma_kernel<<<dim3(16, 8, 16), 256, 0, stream>>>(
      qkv, att, w_pos, g_pos, b_pos, m_pos, v_pos);
  // 3. out = BN(att @ w_proj^T)     [f32 out]
  gemm_bn<true><<<dim3(16, 4, 16), 256, 0, stream>>>(
      att, w_proj, g_proj, b_proj, m_proj, v_proj, nullptr,
      (float*)d_out, 256, 256);
}